// Round 3
// baseline (3014.464 us; speedup 1.0000x reference)
//
#include <hip/hip_runtime.h>
#include <math.h>

// CVQNN classifier, N=64 modes, OUT=10, HBAR=2.
//
// Kernel 1 (1 block, 320 thr): build S (128x128 symplectic, 2 layers) and d.
//   Lane pair (2c, 2c+1) holds column c: half h = t&1 keeps rows [64h,64h+64)
//   in 64 registers. Every BS / rot+squeeze left-multiply mixes row r with
//   row 64+r only -> cross-half values come from __shfl_xor(.,1) (partner is
//   the adjacent lane, same wave). No 128-reg array -> no spills.
//   Column 128 (threads 256,257) carries the displacement vector d.
//   Emits ws: W[k*20+rr] = 2*S[rows[rr],k] (1280 fl), bias[20], cterm[10].
// Kernel 2: 2 rows/thread (r, r+256). Weights staged to LDS once per block;
//   inner loop reads them at wave-uniform addresses (LDS broadcast, no bank
//   conflicts, no SGPR pressure). x via float4 loads; out fp32 float2 stores.

#define LSTRIDE 758
#define OUT_N 10
// per-layer trig table layout (stride 758):
// [0,63) ct [63,126) st [126,189) cp [189,252) sp   (int params, theta/phi)
// [252,315) rot_c [315,378) rot_s [378,442) exp(-sq) [442,506) exp(+sq)
// [506,758) int2 trig (same sublayout)

template<int S>
__device__ __forceinline__ void bs_split(float (&v)[64], float sgn, const float* t){
  #pragma unroll
  for (int i = S; i < 63; i += 2){
    float ct = t[i], st = t[63+i], cp = t[126+i], sp = t[189+i];
    float cs = cp*st, ss = sp*st*sgn;      // sgn = -1 for h=0, +1 for h=1
    float p0 = __shfl_xor(v[i],   1);
    float p1 = __shfl_xor(v[i+1], 1);
    float u0 = v[i], u1 = v[i+1];
    v[i]   = ct*u0 - cs*u1 + ss*p1;
    v[i+1] = cs*u0 + ct*u1 + ss*p0;
  }
}

__device__ __forceinline__ void rot_sq_split(float (&v)[64], int h, const float* t){
  #pragma unroll
  for (int m = 0; m < 64; ++m){
    float cm = (m < 63) ? t[252+m] : 1.0f;
    float sm = (m < 63) ? t[315+m] : 0.0f;
    float e  = h ? t[442+m] : t[378+m];    // exp(+sq) : exp(-sq)
    float p  = __shfl_xor(v[m], 1);
    float u  = v[m];
    v[m] = h ? e*(sm*p + cm*u) : e*(cm*u - sm*p);
  }
}

__global__ __launch_bounds__(320)
void cvqnn_setup(const float* __restrict__ i1_0, const float* __restrict__ sq_0,
                 const float* __restrict__ i2_0, const float* __restrict__ dp_0,
                 const float* __restrict__ i1_1, const float* __restrict__ sq_1,
                 const float* __restrict__ i2_1, const float* __restrict__ dp_1,
                 float* __restrict__ ws)
{
  __shared__ float trig[2*LSTRIDE];
  __shared__ float red[256*OUT_N];
  const int t = threadIdx.x;

  // ---- parallel transcendental precompute ----
  for (int idx = t; idx < 2*LSTRIDE; idx += 320){
    int L = idx / LSTRIDE, q = idx - L*LSTRIDE;
    const float* i1 = L ? i1_1 : i1_0;
    const float* i2 = L ? i2_1 : i2_0;
    const float* sq = L ? sq_1 : sq_0;
    float v;
    if (q < 252){
      int kind = q / 63, i = q - kind*63;
      float ang = (kind & 2) ? i1[3*i+1] : i1[3*i];
      v = (kind & 1) ? sinf(ang) : cosf(ang);
    } else if (q < 378){
      int kind = (q-252)/63, m = (q-252) - kind*63;
      float ang = i1[3*m+2];
      v = kind ? sinf(ang) : cosf(ang);
    } else if (q < 506){
      int kind = (q-378)/64, m = (q-378) - kind*64;
      v = expf(kind ? sq[m] : -sq[m]);
    } else {
      int qq = q - 506;
      int kind = qq / 63, i = qq - kind*63;
      float ang = (kind & 2) ? i2[3*i+1] : i2[3*i];
      v = (kind & 1) ? sinf(ang) : cosf(ang);
    }
    trig[idx] = v;
  }
  __syncthreads();

  const int c = t >> 1, h = t & 1;
  const float sgn = h ? 1.0f : -1.0f;
  float v[64];
  const bool act = (c < 129);

  if (act){
    #pragma unroll
    for (int r = 0; r < 64; ++r) v[r] = (64*h + r == c) ? 1.0f : 0.0f; // c==128 -> 0 (d)

    #pragma unroll
    for (int L = 0; L < 2; ++L){
      const float* tl = trig + L*LSTRIDE;
      bs_split<0>(v, sgn, tl);
      bs_split<1>(v, sgn, tl);
      rot_sq_split(v, h, tl);
      bs_split<0>(v, sgn, tl + 506);
      bs_split<1>(v, sgn, tl + 506);
      if (c == 128 && h == 0){
        const float* dp = L ? dp_1 : dp_0;
        #pragma unroll
        for (int m = 0; m < 64; ++m) v[m] += 2.0f * dp[m];
      }
    }

    // rows of interest: rr<10 -> row rr (h=0, local rr); rr>=10 -> row 64+(rr-10) (h=1)
    if (c < 64){
      #pragma unroll
      for (int w = 0; w < OUT_N; ++w)
        ws[c*20 + h*10 + w] = 2.0f * v[w];           // W[k=c][rr], factor 2 folded
    }
    if (c < 128){
      #pragma unroll
      for (int w = 0; w < OUT_N; ++w)
        red[t*OUT_N + w] = v[w]*v[w];                // S[w,c]^2 (h=0) / S[64+w,c]^2 (h=1)
    }
    if (c == 128){
      #pragma unroll
      for (int w = 0; w < OUT_N; ++w)
        ws[1280 + h*10 + w] = v[w];                  // bias = d[rows]
    }
  }
  __syncthreads();
  if (t < OUT_N){
    float s = 0.0f;
    for (int k = 0; k < 256; ++k) s += red[k*OUT_N + t];
    ws[1300 + t] = s;                                // cov_term[w]
  }
}

// ---------------- main streaming kernel ----------------
__global__ __launch_bounds__(256, 4)
void cvqnn_main(const float* __restrict__ x, const float* __restrict__ ws,
                float* __restrict__ out, int B)
{
  __shared__ float lw[1312];
  const int tid = threadIdx.x;
  for (int i = tid; i < 1310; i += 256) lw[i] = ws[i];
  __syncthreads();

  long r0 = (long)blockIdx.x * 512 + tid;
  long r1 = r0 + 256;
  long rc0 = r0 < B ? r0 : (long)B - 1;
  long rc1 = r1 < B ? r1 : (long)B - 1;

  const float4* xa = reinterpret_cast<const float4*>(x + rc0*64);
  const float4* xb = reinterpret_cast<const float4*>(x + rc1*64);

  float acc0[20], acc1[20];
  #pragma unroll
  for (int r = 0; r < 20; ++r){ float bb = lw[1280+r]; acc0[r] = bb; acc1[r] = bb; }

  #pragma unroll
  for (int k4 = 0; k4 < 16; ++k4){
    float4 va = xa[k4];
    float4 vb = xb[k4];
    const float* wk = lw + k4*80;     // W rows 4k4..4k4+3, r-contiguous (stride 20)
    #pragma unroll
    for (int r = 0; r < 20; ++r){
      float w0 = wk[r], w1 = wk[20+r], w2 = wk[40+r], w3 = wk[60+r];
      acc0[r] += va.x*w0 + va.y*w1 + va.z*w2 + va.w*w3;
      acc1[r] += vb.x*w0 + vb.y*w1 + vb.z*w2 + vb.w*w3;
    }
  }

  #pragma unroll
  for (int pass = 0; pass < 2; ++pass){
    long r = pass ? r1 : r0;
    if (r >= B) continue;
    float* acc = pass ? acc1 : acc0;
    float2* o = reinterpret_cast<float2*>(out + r*10);
    #pragma unroll
    for (int w = 0; w < OUT_N; w += 2){
      float mx0 = acc[w],   mp0 = acc[10+w];
      float nm0 = (lw[1300+w]   + mx0*mx0 + mp0*mp0) * 0.25f - 0.5f;
      float mx1 = acc[w+1], mp1 = acc[11+w];
      float nm1 = (lw[1301+w]   + mx1*mx1 + mp1*mp1) * 0.25f - 0.5f;
      o[w >> 1] = make_float2(log1pf(fmaxf(nm0, 0.0f)), log1pf(fmaxf(nm1, 0.0f)));
    }
  }
}

extern "C" void kernel_launch(void* const* d_in, const int* in_sizes, int n_in,
                              void* d_out, int out_size, void* d_ws, size_t ws_size,
                              hipStream_t stream)
{
  const float* x    = (const float*)d_in[0];
  const float* i1_0 = (const float*)d_in[1];
  const float* sq_0 = (const float*)d_in[2];
  const float* i2_0 = (const float*)d_in[3];
  const float* dp_0 = (const float*)d_in[4];
  const float* i1_1 = (const float*)d_in[5];
  const float* sq_1 = (const float*)d_in[6];
  const float* i2_1 = (const float*)d_in[7];
  const float* dp_1 = (const float*)d_in[8];
  float* ws = (float*)d_ws;

  int B = in_sizes[0] / 64;

  cvqnn_setup<<<1, 320, 0, stream>>>(i1_0, sq_0, i2_0, dp_0,
                                     i1_1, sq_1, i2_1, dp_1, ws);

  int grid = (B + 511) / 512;
  cvqnn_main<<<grid, 256, 0, stream>>>(x, ws, (float*)d_out, B);
}

// Round 4
// 2749.288 us; speedup vs baseline: 1.0965x; 1.0965x over previous
//
#include <hip/hip_runtime.h>
#include <math.h>

// CVQNN classifier, N=64 modes, OUT=10, HBAR=2.
//
// Kernel 1 (1 block, 320 thr): build S (128x128 symplectic, 2 layers) and d.
//   Lane pair (2c, 2c+1) holds column c: half h = t&1 keeps rows [64h,64h+64)
//   in 64 registers; cross-half values via __shfl_xor(.,1).
//   Column 128 (threads 256,257) carries the displacement vector d.
//   Emits ws: W4[(k4*20+r)*4+kk] = 2*S[rows[r],4*k4+kk]  (1280 fl, float4-able),
//             bias[20] @1280, cterm[10] @1300.
// Kernel 2: 4 rows/thread. Weights staged to LDS once per block and read as
//   wave-uniform float4 (ds_read_b128 broadcast). ALL accumulator indices are
//   compile-time constants -> registers (r3's runtime `pass ? acc1 : acc0`
//   select spilled both arrays to scratch: 8.6 GB HBM traffic, 2750 us).

#define LSTRIDE 758
#define OUT_N 10
// per-layer trig table layout (stride 758):
// [0,63) ct [63,126) st [126,189) cp [189,252) sp   (int params, theta/phi)
// [252,315) rot_c [315,378) rot_s [378,442) exp(-sq) [442,506) exp(+sq)
// [506,758) int2 trig (same sublayout)

template<int S>
__device__ __forceinline__ void bs_split(float (&v)[64], float sgn, const float* t){
  #pragma unroll
  for (int i = S; i < 63; i += 2){
    float ct = t[i], st = t[63+i], cp = t[126+i], sp = t[189+i];
    float cs = cp*st, ss = sp*st*sgn;      // sgn = -1 for h=0, +1 for h=1
    float p0 = __shfl_xor(v[i],   1);
    float p1 = __shfl_xor(v[i+1], 1);
    float u0 = v[i], u1 = v[i+1];
    v[i]   = ct*u0 - cs*u1 + ss*p1;
    v[i+1] = cs*u0 + ct*u1 + ss*p0;
  }
}

__device__ __forceinline__ void rot_sq_split(float (&v)[64], int h, const float* t){
  #pragma unroll
  for (int m = 0; m < 64; ++m){
    float cm = (m < 63) ? t[252+m] : 1.0f;
    float sm = (m < 63) ? t[315+m] : 0.0f;
    float e  = h ? t[442+m] : t[378+m];    // exp(+sq) : exp(-sq)
    float p  = __shfl_xor(v[m], 1);
    float u  = v[m];
    v[m] = h ? e*(sm*p + cm*u) : e*(cm*u - sm*p);
  }
}

__global__ __launch_bounds__(320)
void cvqnn_setup(const float* __restrict__ i1_0, const float* __restrict__ sq_0,
                 const float* __restrict__ i2_0, const float* __restrict__ dp_0,
                 const float* __restrict__ i1_1, const float* __restrict__ sq_1,
                 const float* __restrict__ i2_1, const float* __restrict__ dp_1,
                 float* __restrict__ ws)
{
  __shared__ float trig[2*LSTRIDE];
  __shared__ float red[256*OUT_N];
  const int t = threadIdx.x;

  // ---- parallel transcendental precompute ----
  for (int idx = t; idx < 2*LSTRIDE; idx += 320){
    int L = idx / LSTRIDE, q = idx - L*LSTRIDE;
    const float* i1 = L ? i1_1 : i1_0;
    const float* i2 = L ? i2_1 : i2_0;
    const float* sq = L ? sq_1 : sq_0;
    float v;
    if (q < 252){
      int kind = q / 63, i = q - kind*63;
      float ang = (kind & 2) ? i1[3*i+1] : i1[3*i];
      v = (kind & 1) ? sinf(ang) : cosf(ang);
    } else if (q < 378){
      int kind = (q-252)/63, m = (q-252) - kind*63;
      float ang = i1[3*m+2];
      v = kind ? sinf(ang) : cosf(ang);
    } else if (q < 506){
      int kind = (q-378)/64, m = (q-378) - kind*64;
      v = expf(kind ? sq[m] : -sq[m]);
    } else {
      int qq = q - 506;
      int kind = qq / 63, i = qq - kind*63;
      float ang = (kind & 2) ? i2[3*i+1] : i2[3*i];
      v = (kind & 1) ? sinf(ang) : cosf(ang);
    }
    trig[idx] = v;
  }
  __syncthreads();

  const int c = t >> 1, h = t & 1;
  const float sgn = h ? 1.0f : -1.0f;
  float v[64];

  if (c < 129){
    #pragma unroll
    for (int r = 0; r < 64; ++r) v[r] = (64*h + r == c) ? 1.0f : 0.0f; // c==128 -> 0 (d)

    #pragma unroll
    for (int L = 0; L < 2; ++L){
      const float* tl = trig + L*LSTRIDE;
      bs_split<0>(v, sgn, tl);
      bs_split<1>(v, sgn, tl);
      rot_sq_split(v, h, tl);
      bs_split<0>(v, sgn, tl + 506);
      bs_split<1>(v, sgn, tl + 506);
      if (c == 128 && h == 0){
        const float* dp = L ? dp_1 : dp_0;
        #pragma unroll
        for (int m = 0; m < 64; ++m) v[m] += 2.0f * dp[m];
      }
    }

    // rows of interest: rr<10 -> row rr (h=0); rr>=10 -> row 64+(rr-10) (h=1)
    if (c < 64){
      // quad-contiguous layout: W4[(k4*20 + r)*4 + kk], k4=c>>2, kk=c&3
      #pragma unroll
      for (int w = 0; w < OUT_N; ++w)
        ws[(((c >> 2) * 20) + h*10 + w) * 4 + (c & 3)] = 2.0f * v[w];
    }
    if (c < 128){
      #pragma unroll
      for (int w = 0; w < OUT_N; ++w)
        red[t*OUT_N + w] = v[w]*v[w];                // S[w,c]^2 / S[64+w,c]^2
    }
    if (c == 128){
      #pragma unroll
      for (int w = 0; w < OUT_N; ++w)
        ws[1280 + h*10 + w] = v[w];                  // bias = d[rows]
    }
  }
  __syncthreads();
  if (t < OUT_N){
    float s = 0.0f;
    for (int k = 0; k < 256; ++k) s += red[k*OUT_N + t];
    ws[1300 + t] = s;                                // cov_term[w]
  }
}

// ---------------- main streaming kernel: 4 rows/thread ----------------
__global__ __launch_bounds__(256, 2)
void cvqnn_main(const float* __restrict__ x, const float* __restrict__ ws,
                float* __restrict__ out, int B)
{
  __shared__ __align__(16) float lw[1312];
  const int tid = threadIdx.x;
  for (int i = tid; i < 1310; i += 256) lw[i] = ws[i];
  __syncthreads();

  const long r0 = (long)blockIdx.x * 1024 + tid;

  const float4* xp0; const float4* xp1; const float4* xp2; const float4* xp3;
  {
    long ra = r0           < B ? r0           : (long)B - 1;
    long rb = r0 + 256     < B ? r0 + 256     : (long)B - 1;
    long rc = r0 + 512     < B ? r0 + 512     : (long)B - 1;
    long rd = r0 + 768     < B ? r0 + 768     : (long)B - 1;
    xp0 = reinterpret_cast<const float4*>(x + ra*64);
    xp1 = reinterpret_cast<const float4*>(x + rb*64);
    xp2 = reinterpret_cast<const float4*>(x + rc*64);
    xp3 = reinterpret_cast<const float4*>(x + rd*64);
  }

  float acc[4][20];
  #pragma unroll
  for (int r = 0; r < 20; ++r){
    float bb = lw[1280 + r];
    acc[0][r] = bb; acc[1][r] = bb; acc[2][r] = bb; acc[3][r] = bb;
  }

  const float4* wq = reinterpret_cast<const float4*>(lw);
  #pragma unroll
  for (int k4 = 0; k4 < 16; ++k4){
    float4 a = xp0[k4], b = xp1[k4], c = xp2[k4], d = xp3[k4];
    #pragma unroll
    for (int r = 0; r < 20; ++r){
      float4 w = wq[k4*20 + r];                      // wave-uniform ds_read_b128
      acc[0][r] += a.x*w.x + a.y*w.y + a.z*w.z + a.w*w.w;
      acc[1][r] += b.x*w.x + b.y*w.y + b.z*w.z + b.w*w.w;
      acc[2][r] += c.x*w.x + c.y*w.y + c.z*w.z + c.w*w.w;
      acc[3][r] += d.x*w.x + d.y*w.y + d.z*w.z + d.w*w.w;
    }
  }

  #pragma unroll
  for (int p = 0; p < 4; ++p){
    long r = r0 + 256*p;
    if (r < B){
      float2* o = reinterpret_cast<float2*>(out + r*10);
      #pragma unroll
      for (int w = 0; w < OUT_N; w += 2){
        float mx0 = acc[p][w],   mp0 = acc[p][10+w];
        float nm0 = (lw[1300+w] + mx0*mx0 + mp0*mp0) * 0.25f - 0.5f;
        float mx1 = acc[p][w+1], mp1 = acc[p][11+w];
        float nm1 = (lw[1301+w] + mx1*mx1 + mp1*mp1) * 0.25f - 0.5f;
        o[w >> 1] = make_float2(log1pf(fmaxf(nm0, 0.0f)), log1pf(fmaxf(nm1, 0.0f)));
      }
    }
  }
}

extern "C" void kernel_launch(void* const* d_in, const int* in_sizes, int n_in,
                              void* d_out, int out_size, void* d_ws, size_t ws_size,
                              hipStream_t stream)
{
  const float* x    = (const float*)d_in[0];
  const float* i1_0 = (const float*)d_in[1];
  const float* sq_0 = (const float*)d_in[2];
  const float* i2_0 = (const float*)d_in[3];
  const float* dp_0 = (const float*)d_in[4];
  const float* i1_1 = (const float*)d_in[5];
  const float* sq_1 = (const float*)d_in[6];
  const float* i2_1 = (const float*)d_in[7];
  const float* dp_1 = (const float*)d_in[8];
  float* ws = (float*)d_ws;

  int B = in_sizes[0] / 64;

  cvqnn_setup<<<1, 320, 0, stream>>>(i1_0, sq_0, i2_0, dp_0,
                                     i1_1, sq_1, i2_1, dp_1, ws);

  int grid = (B + 1023) / 1024;
  cvqnn_main<<<grid, 256, 0, stream>>>(x, ws, (float*)d_out, B);
}